// Round 4
// baseline (216.308 us; speedup 1.0000x reference)
//
#include <hip/hip_runtime.h>
#include <math.h>

typedef __attribute__((ext_vector_type(8))) short bf16x8;
typedef __attribute__((ext_vector_type(16))) float f32x16;
typedef __attribute__((ext_vector_type(4))) float vf4;
typedef __attribute__((ext_vector_type(4))) unsigned int u32x4;

__device__ __forceinline__ float wave_reduce(float v) {
#pragma unroll
    for (int off = 32; off > 0; off >>= 1) v += __shfl_down(v, off, 64);
    return v;
}

// truncation fp32->bf16 pack: two floats -> one dword (hi16(f1)<<16 | hi16(f0)).
__device__ __forceinline__ unsigned int pk_trunc(float f0, float f1) {
    unsigned u0 = __float_as_uint(f0), u1 = __float_as_uint(f1);
    return (u1 & 0xFFFF0000u) | (u0 >> 16);
}

// Fused angular+center, two launches.
// R13 analysis: iteration decomposes as 2x512MiB poison fills (155.8us, fixed,
// gaps ~0.3us) + fused ~48us + reduce ~4us. fused's 48us (= 2.7 TB/s for the
// 134MB feat stream) was INVARIANT across nb=2048/8192, full/tri ang, and
// rolled/unrolled center. The one invariant suspect: __builtin_nontemporal_load
// on the stream. R2's counters proved partial L3 residency of inputs
// (FETCH=75.7MB < 137MB footprint); nt reads bypass cache allocation and
// plausibly the L3 read path, forcing HBM fetch of L3-resident data.
// R13 changes:
//  1. nt loads -> plain loads (let the 256MiB L3 serve re-resident feat).
//  2. Center phase FIRST, ang after (stream starts at t=0 on all blocks; the
//     ~5us ang tiles hide under the center tail). Bit-exact: partial =
//     center+ang is IEEE-commutative with ang+center; internal orders kept.
__global__ __launch_bounds__(256) void fused_kernel(const int* __restrict__ y,
                                                    const vf4* __restrict__ feat4,
                                                    const vf4* __restrict__ cent4,
                                                    float* __restrict__ partials,
                                                    int n4, int d4, float cen_scale,
                                                    int C, int ntile32, int ntri,
                                                    int steps16, float ct, float ang_scale) {
    const int bid = blockIdx.x;
    const int lane = threadIdx.x & 63;
    const int wid = threadIdx.x >> 6;
    __shared__ float sm[4];

    float partial = 0.f;

    // ---------------- center: grid-stride over float4 elements of feat ----------------
    {
        const int stride = gridDim.x * 256;
        float cs = 0.f;
        int i = bid * 256 + threadIdx.x;
        const bool fast = ((stride % d4) == 0) && ((d4 & 63) == 0) && (n4 == 4 * stride);
        if (fast) {
            // exactly 4 iters/thread, all threads in-range, row wave-uniform.
            int row = i / d4;
            const int col = i - row * d4;
            const int rstep = stride / d4;
            // issue all feat streams first
            const vf4 f0 = feat4[i];
            const vf4 f1 = feat4[i + stride];
            const vf4 f2 = feat4[i + 2 * stride];
            const vf4 f3 = feat4[i + 3 * stride];
            // scalar class ids (row is wave-uniform: d4 % 64 == 0)
            const int r0 = __builtin_amdgcn_readfirstlane(row);
            const int cls0 = y[r0];
            const int cls1 = y[r0 + rstep];
            const int cls2 = y[r0 + 2 * rstep];
            const int cls3 = y[r0 + 3 * rstep];
            const vf4 g0 = cent4[(size_t)cls0 * d4 + col];
            const vf4 g1 = cent4[(size_t)cls1 * d4 + col];
            const vf4 g2 = cent4[(size_t)cls2 * d4 + col];
            const vf4 g3 = cent4[(size_t)cls3 * d4 + col];
            float dx, dy, dz, dw;
            dx = f0.x - g0.x; dy = f0.y - g0.y; dz = f0.z - g0.z; dw = f0.w - g0.w;
            cs += dx * dx + dy * dy + dz * dz + dw * dw;
            dx = f1.x - g1.x; dy = f1.y - g1.y; dz = f1.z - g1.z; dw = f1.w - g1.w;
            cs += dx * dx + dy * dy + dz * dz + dw * dw;
            dx = f2.x - g2.x; dy = f2.y - g2.y; dz = f2.z - g2.z; dw = f2.w - g2.w;
            cs += dx * dx + dy * dy + dz * dz + dw * dw;
            dx = f3.x - g3.x; dy = f3.y - g3.y; dz = f3.z - g3.z; dw = f3.w - g3.w;
            cs += dx * dx + dy * dy + dz * dz + dw * dw;
        } else {
            for (; i < n4; i += stride) {
                int row = i / d4;
                int col = i - row * d4;
                const int cls = y[row];
                vf4 f = feat4[i];
                vf4 c = cent4[(size_t)cls * d4 + col];
                float dx = f.x - c.x, dy = f.y - c.y, dz = f.z - c.z, dw = f.w - c.w;
                cs += dx * dx + dy * dy + dz * dz + dw * dw;
            }
        }
        partial = cs * cen_scale;
    }

    // ---------------- angular: one upper-tri 32x32 tile per wave ----------------
    const int t = bid * 4 + wid;            // global wave id == triangular tile id
    if (t < ntri) {
        const int N = ntile32;
        // decode t -> (ti,tj), ti<=tj; base(ti)=ti*N - ti*(ti-1)/2
        const float ff = (float)((2 * N + 1) * (2 * N + 1) - 8 * t);
        int ti = (int)(((float)(2 * N + 1) - sqrtf(ff)) * 0.5f);
        int base = ti * N - (ti * (ti - 1)) / 2;
        if (t < base) {
            --ti; base = ti * N - (ti * (ti - 1)) / 2;
        } else {
            const int nxt = (ti + 1) * N - ((ti + 1) * ti) / 2;
            if (t >= nxt) { ++ti; base = nxt; }
        }
        const int tj = ti + (t - base);

        const int m = lane & 31;            // A/B row within panel
        const int half = lane >> 5;         // k-half selector
        const int ra = ti * 32 + m;
        const int rb = tj * 32 + m;
        const bool va = ra < C;
        const bool vb = rb < C;
        const vf4* aptr = cent4 + (size_t)ra * d4 + half * 2;
        const vf4* bptr = cent4 + (size_t)rb * d4 + half * 2;
        f32x16 acc;
#pragma unroll
        for (int k = 0; k < 16; ++k) acc[k] = 0.f;
        float sa = 0.f, sb = 0.f;
#pragma unroll 4
        for (int st = 0; st < steps16; ++st) {
            vf4 a0 = {0.f, 0.f, 0.f, 0.f}, a1 = a0, b0 = a0, b1 = a0;
            if (va) { a0 = aptr[st * 4]; a1 = aptr[st * 4 + 1]; }
            if (vb) { b0 = bptr[st * 4]; b1 = bptr[st * 4 + 1]; }
            sa += a0.x * a0.x + a0.y * a0.y + a0.z * a0.z + a0.w * a0.w
                + a1.x * a1.x + a1.y * a1.y + a1.z * a1.z + a1.w * a1.w;
            sb += b0.x * b0.x + b0.y * b0.y + b0.z * b0.z + b0.w * b0.w
                + b1.x * b1.x + b1.y * b1.y + b1.z * b1.z + b1.w * b1.w;
            u32x4 ap, bp;
            ap.x = pk_trunc(a0.x, a0.y); ap.y = pk_trunc(a0.z, a0.w);
            ap.z = pk_trunc(a1.x, a1.y); ap.w = pk_trunc(a1.z, a1.w);
            bp.x = pk_trunc(b0.x, b0.y); bp.y = pk_trunc(b0.z, b0.w);
            bp.z = pk_trunc(b1.x, b1.y); bp.w = pk_trunc(b1.z, b1.w);
            bf16x8 af = __builtin_bit_cast(bf16x8, ap);
            bf16x8 bf = __builtin_bit_cast(bf16x8, bp);
            acc = __builtin_amdgcn_mfma_f32_32x32x16_bf16(af, bf, acc, 0, 0, 0);
        }
        // combine the two k-halves of each row norm: lanes l and l^32 share row l&31
        sa += __shfl_xor(sa, 32, 64);
        sb += __shfl_xor(sb, 32, 64);
        // C/D layout (measured m74/m101): col = lane&31, row = (reg&3)+8*(reg>>2)+4*half
        const int gj = tj * 32 + m;
        const float dj = sb;                // norm of B row gj (col of this lane)
        float local = 0.f;
#pragma unroll
        for (int reg = 0; reg < 16; ++reg) {
            const int r = (reg & 3) + 8 * (reg >> 2) + 4 * half;
            const int gi = ti * 32 + r;
            const float di = __shfl(sa, r, 64);   // lane r holds norm of A row r
            if (gi < C && gj < C && gi != gj) {
                float sim = acc[reg] * rsqrtf(di * dj);
                float dlt = sim - ct;
                local += dlt * dlt;
            }
        }
        const float w = (ti == tj) ? 1.f : 2.f;   // off-diag tiles stand in for their mirror
        partial += local * (ang_scale * w);
    }

    // block reduce -> plain store to partials[bid] (no atomics anywhere)
    float r = wave_reduce(partial);
    if (lane == 0) sm[wid] = r;
    __syncthreads();
    if (threadIdx.x == 0) {
        partials[bid] = sm[0] + sm[1] + sm[2] + sm[3];
    }
}

// Kernel 2: single block reduces nb partials -> out[0] (plain store).
__global__ __launch_bounds__(256) void reduce_kernel(const float* __restrict__ partials,
                                                     float* __restrict__ out, int nb) {
    __shared__ float sm[4];
    const int lane = threadIdx.x & 63;
    const int wid = threadIdx.x >> 6;
    float s = 0.f;
    for (int i = threadIdx.x; i < nb; i += 256) s += partials[i];
    s = wave_reduce(s);
    if (lane == 0) sm[wid] = s;
    __syncthreads();
    if (threadIdx.x == 0) out[0] = sm[0] + sm[1] + sm[2] + sm[3];
}

extern "C" void kernel_launch(void* const* d_in, const int* in_sizes, int n_in,
                              void* d_out, int out_size, void* d_ws, size_t ws_size,
                              hipStream_t stream) {
    const int* y = (const int*)d_in[0];
    const float* feat = (const float*)d_in[1];
    const float* centers = (const float*)d_in[2];

    const int B = in_sizes[0];
    const int D = in_sizes[1] / B;
    const int C = in_sizes[2] / D;
    const int d4 = D / 4;
    const int ntile32 = (C + 31) / 32;
    const int ntri = ntile32 * (ntile32 + 1) / 2;   // 528 upper-tri tiles for C=1000

    // ct = costheta(C): static recurrence in double, matches Python reference.
    const int nd = C - 1;
    double r = 0.0;
    if (nd >= 2) {
        r = 0.5;
        for (int i = 3; i <= nd; ++i) r = 0.5 / sqrt(1.0 - r * r);
    }
    const float ct = (float)(2.0 * r * r - 1.0);

    const float cen_scale = (float)(0.5 / (double)B);
    const float ang_scale = (float)(1.0 / (0.5 * (double)C * (double)(C - 1)));

    float* partials = (float*)d_ws;
    const int nb = 8192;   // 4 center iters/thread (n4 == 4*stride for B=65536,D=512);
                           // ang on waves 0..527 (blocks 0..131), after center phase

    fused_kernel<<<nb, 256, 0, stream>>>(
        y, (const vf4*)feat, (const vf4*)centers, partials,
        B * d4, d4, cen_scale, C, ntile32, ntri, D / 16, ct, ang_scale);

    reduce_kernel<<<1, 256, 0, stream>>>(partials, (float*)d_out, nb);
}

// Round 5
// 213.827 us; speedup vs baseline: 1.0116x; 1.0116x over previous
//
#include <hip/hip_runtime.h>
#include <math.h>

typedef __attribute__((ext_vector_type(8))) short bf16x8;
typedef __attribute__((ext_vector_type(16))) float f32x16;
typedef __attribute__((ext_vector_type(4))) float vf4;
typedef __attribute__((ext_vector_type(4))) unsigned int u32x4;

__device__ __forceinline__ float wave_reduce(float v) {
#pragma unroll
    for (int off = 32; off > 0; off >>= 1) v += __shfl_down(v, off, 64);
    return v;
}

// truncation fp32->bf16 pack: two floats -> one dword (hi16(f1)<<16 | hi16(f0)).
__device__ __forceinline__ unsigned int pk_trunc(float f0, float f1) {
    unsigned u0 = __float_as_uint(f0), u1 = __float_as_uint(f1);
    return (u1 & 0xFFFF0000u) | (u0 >> 16);
}

// Fused angular+center, two launches.
// R14: single-lever A/B vs R12 (208.3us): ONLY change is nontemporal feat
// loads -> plain loads. R13 bundled this with a phase reorder (216.3us,
// confounded). Two rival mechanisms:
//  M1: nt reads ride a low-concurrency no-allocate path -> plain is faster.
//  M2: plain feat loads sweep L2 and thrash the (equal-volume) center gather
//      -> nt is protective.
// This round discriminates them. Everything else is byte-identical to R12:
// ang-first, 528 upper-tri 32x32 gram tiles (off-diag weight 2), exactly-4
// unrolled center iters with scalar cls via readfirstlane, two launches,
// no atomics/fences (R11 showed per-block __threadfence = L2-inv storm).
__global__ __launch_bounds__(256) void fused_kernel(const int* __restrict__ y,
                                                    const vf4* __restrict__ feat4,
                                                    const vf4* __restrict__ cent4,
                                                    float* __restrict__ partials,
                                                    int n4, int d4, float cen_scale,
                                                    int C, int ntile32, int ntri,
                                                    int steps16, float ct, float ang_scale) {
    const int bid = blockIdx.x;
    const int lane = threadIdx.x & 63;
    const int wid = threadIdx.x >> 6;
    __shared__ float sm[4];

    float partial = 0.f;

    // ---------------- angular: one upper-tri 32x32 tile per wave ----------------
    const int t = bid * 4 + wid;            // global wave id == triangular tile id
    if (t < ntri) {
        const int N = ntile32;
        // decode t -> (ti,tj), ti<=tj; base(ti)=ti*N - ti*(ti-1)/2
        const float ff = (float)((2 * N + 1) * (2 * N + 1) - 8 * t);
        int ti = (int)(((float)(2 * N + 1) - sqrtf(ff)) * 0.5f);
        int base = ti * N - (ti * (ti - 1)) / 2;
        if (t < base) {
            --ti; base = ti * N - (ti * (ti - 1)) / 2;
        } else {
            const int nxt = (ti + 1) * N - ((ti + 1) * ti) / 2;
            if (t >= nxt) { ++ti; base = nxt; }
        }
        const int tj = ti + (t - base);

        const int m = lane & 31;            // A/B row within panel
        const int half = lane >> 5;         // k-half selector
        const int ra = ti * 32 + m;
        const int rb = tj * 32 + m;
        const bool va = ra < C;
        const bool vb = rb < C;
        const vf4* aptr = cent4 + (size_t)ra * d4 + half * 2;
        const vf4* bptr = cent4 + (size_t)rb * d4 + half * 2;
        f32x16 acc;
#pragma unroll
        for (int k = 0; k < 16; ++k) acc[k] = 0.f;
        float sa = 0.f, sb = 0.f;
#pragma unroll 4
        for (int st = 0; st < steps16; ++st) {
            vf4 a0 = {0.f, 0.f, 0.f, 0.f}, a1 = a0, b0 = a0, b1 = a0;
            if (va) { a0 = aptr[st * 4]; a1 = aptr[st * 4 + 1]; }
            if (vb) { b0 = bptr[st * 4]; b1 = bptr[st * 4 + 1]; }
            sa += a0.x * a0.x + a0.y * a0.y + a0.z * a0.z + a0.w * a0.w
                + a1.x * a1.x + a1.y * a1.y + a1.z * a1.z + a1.w * a1.w;
            sb += b0.x * b0.x + b0.y * b0.y + b0.z * b0.z + b0.w * b0.w
                + b1.x * b1.x + b1.y * b1.y + b1.z * b1.z + b1.w * b1.w;
            u32x4 ap, bp;
            ap.x = pk_trunc(a0.x, a0.y); ap.y = pk_trunc(a0.z, a0.w);
            ap.z = pk_trunc(a1.x, a1.y); ap.w = pk_trunc(a1.z, a1.w);
            bp.x = pk_trunc(b0.x, b0.y); bp.y = pk_trunc(b0.z, b0.w);
            bp.z = pk_trunc(b1.x, b1.y); bp.w = pk_trunc(b1.z, b1.w);
            bf16x8 af = __builtin_bit_cast(bf16x8, ap);
            bf16x8 bf = __builtin_bit_cast(bf16x8, bp);
            acc = __builtin_amdgcn_mfma_f32_32x32x16_bf16(af, bf, acc, 0, 0, 0);
        }
        // combine the two k-halves of each row norm: lanes l and l^32 share row l&31
        sa += __shfl_xor(sa, 32, 64);
        sb += __shfl_xor(sb, 32, 64);
        // C/D layout (measured m74/m101): col = lane&31, row = (reg&3)+8*(reg>>2)+4*half
        const int gj = tj * 32 + m;
        const float dj = sb;                // norm of B row gj (col of this lane)
        float local = 0.f;
#pragma unroll
        for (int reg = 0; reg < 16; ++reg) {
            const int r = (reg & 3) + 8 * (reg >> 2) + 4 * half;
            const int gi = ti * 32 + r;
            const float di = __shfl(sa, r, 64);   // lane r holds norm of A row r
            if (gi < C && gj < C && gi != gj) {
                float sim = acc[reg] * rsqrtf(di * dj);
                float dlt = sim - ct;
                local += dlt * dlt;
            }
        }
        const float w = (ti == tj) ? 1.f : 2.f;   // off-diag tiles stand in for their mirror
        partial = local * (ang_scale * w);
    }

    // ---------------- center: grid-stride over float4 elements of feat ----------------
    {
        const int stride = gridDim.x * 256;
        float cs = 0.f;
        int i = bid * 256 + threadIdx.x;
        const bool fast = ((stride % d4) == 0) && ((d4 & 63) == 0) && (n4 == 4 * stride);
        if (fast) {
            // exactly 4 iters/thread, all threads in-range, row wave-uniform.
            int row = i / d4;
            const int col = i - row * d4;
            const int rstep = stride / d4;
            // issue all feat streams first (PLAIN loads this round — the A/B lever)
            const vf4 f0 = feat4[i];
            const vf4 f1 = feat4[i + stride];
            const vf4 f2 = feat4[i + 2 * stride];
            const vf4 f3 = feat4[i + 3 * stride];
            // scalar class ids (row is wave-uniform: d4 % 64 == 0)
            const int r0 = __builtin_amdgcn_readfirstlane(row);
            const int cls0 = y[r0];
            const int cls1 = y[r0 + rstep];
            const int cls2 = y[r0 + 2 * rstep];
            const int cls3 = y[r0 + 3 * rstep];
            const vf4 g0 = cent4[(size_t)cls0 * d4 + col];
            const vf4 g1 = cent4[(size_t)cls1 * d4 + col];
            const vf4 g2 = cent4[(size_t)cls2 * d4 + col];
            const vf4 g3 = cent4[(size_t)cls3 * d4 + col];
            float dx, dy, dz, dw;
            dx = f0.x - g0.x; dy = f0.y - g0.y; dz = f0.z - g0.z; dw = f0.w - g0.w;
            cs += dx * dx + dy * dy + dz * dz + dw * dw;
            dx = f1.x - g1.x; dy = f1.y - g1.y; dz = f1.z - g1.z; dw = f1.w - g1.w;
            cs += dx * dx + dy * dy + dz * dz + dw * dw;
            dx = f2.x - g2.x; dy = f2.y - g2.y; dz = f2.z - g2.z; dw = f2.w - g2.w;
            cs += dx * dx + dy * dy + dz * dz + dw * dw;
            dx = f3.x - g3.x; dy = f3.y - g3.y; dz = f3.z - g3.z; dw = f3.w - g3.w;
            cs += dx * dx + dy * dy + dz * dz + dw * dw;
        } else {
            for (; i < n4; i += stride) {
                int row = i / d4;
                int col = i - row * d4;
                const int cls = y[row];
                vf4 f = feat4[i];
                vf4 c = cent4[(size_t)cls * d4 + col];
                float dx = f.x - c.x, dy = f.y - c.y, dz = f.z - c.z, dw = f.w - c.w;
                cs += dx * dx + dy * dy + dz * dz + dw * dw;
            }
        }
        partial += cs * cen_scale;
    }

    // block reduce -> plain store to partials[bid] (no atomics anywhere)
    float r = wave_reduce(partial);
    if (lane == 0) sm[wid] = r;
    __syncthreads();
    if (threadIdx.x == 0) {
        partials[bid] = sm[0] + sm[1] + sm[2] + sm[3];
    }
}

// Kernel 2: single block reduces nb partials -> out[0] (plain store).
__global__ __launch_bounds__(256) void reduce_kernel(const float* __restrict__ partials,
                                                     float* __restrict__ out, int nb) {
    __shared__ float sm[4];
    const int lane = threadIdx.x & 63;
    const int wid = threadIdx.x >> 6;
    float s = 0.f;
    for (int i = threadIdx.x; i < nb; i += 256) s += partials[i];
    s = wave_reduce(s);
    if (lane == 0) sm[wid] = s;
    __syncthreads();
    if (threadIdx.x == 0) out[0] = sm[0] + sm[1] + sm[2] + sm[3];
}

extern "C" void kernel_launch(void* const* d_in, const int* in_sizes, int n_in,
                              void* d_out, int out_size, void* d_ws, size_t ws_size,
                              hipStream_t stream) {
    const int* y = (const int*)d_in[0];
    const float* feat = (const float*)d_in[1];
    const float* centers = (const float*)d_in[2];

    const int B = in_sizes[0];
    const int D = in_sizes[1] / B;
    const int C = in_sizes[2] / D;
    const int d4 = D / 4;
    const int ntile32 = (C + 31) / 32;
    const int ntri = ntile32 * (ntile32 + 1) / 2;   // 528 upper-tri tiles for C=1000

    // ct = costheta(C): static recurrence in double, matches Python reference.
    const int nd = C - 1;
    double r = 0.0;
    if (nd >= 2) {
        r = 0.5;
        for (int i = 3; i <= nd; ++i) r = 0.5 / sqrt(1.0 - r * r);
    }
    const float ct = (float)(2.0 * r * r - 1.0);

    const float cen_scale = (float)(0.5 / (double)B);
    const float ang_scale = (float)(1.0 / (0.5 * (double)C * (double)(C - 1)));

    float* partials = (float*)d_ws;
    const int nb = 8192;   // 4 center iters/thread (n4 == 4*stride for B=65536,D=512);
                           // ang on waves 0..527 (blocks 0..131)

    fused_kernel<<<nb, 256, 0, stream>>>(
        y, (const vf4*)feat, (const vf4*)centers, partials,
        B * d4, d4, cen_scale, C, ntile32, ntri, D / 16, ct, ang_scale);

    reduce_kernel<<<1, 256, 0, stream>>>(partials, (float*)d_out, nb);
}

// Round 6
// 207.064 us; speedup vs baseline: 1.0446x; 1.0327x over previous
//
#include <hip/hip_runtime.h>
#include <math.h>

typedef __attribute__((ext_vector_type(8))) short bf16x8;
typedef __attribute__((ext_vector_type(16))) float f32x16;
typedef __attribute__((ext_vector_type(4))) float vf4;
typedef __attribute__((ext_vector_type(4))) unsigned int u32x4;

__device__ __forceinline__ float wave_reduce(float v) {
#pragma unroll
    for (int off = 32; off > 0; off >>= 1) v += __shfl_down(v, off, 64);
    return v;
}

// truncation fp32->bf16 pack: two floats -> one dword (hi16(f1)<<16 | hi16(f0)).
__device__ __forceinline__ unsigned int pk_trunc(float f0, float f1) {
    unsigned u0 = __float_as_uint(f0), u1 = __float_as_uint(f1);
    return (u1 & 0xFFFF0000u) | (u0 >> 16);
}

// Fused angular+center, two launches. R15 == R12 (best measured: 208.3us).
// Ledger of A/B results on this problem (dur_us includes ~155.8us of fixed
// harness poison fills; controllable part ~52us):
//   nb 2048->8192:            0      (scheduling-invariant)
//   tri-ang + unrolled center: -1.3  (kept)
//   per-block __threadfence:  +360   (L2-inv storm; NEVER single-launch)
//   nt -> plain feat loads:   +5.5   (plain thrashes the center gather's L2
//                                     residency; nt is protective — M2)
//   center-first reorder:     +2.5   (ang-first warms centers into L2)
// Structure: ang-first (528 upper-tri 32x32 gram tiles via one
// mfma_f32_32x32x16_bf16 per wave, off-diag weight 2, in-flight fp32->bf16
// truncation, in-register row norms); center = exactly-4 unrolled grid-stride
// iters, nontemporal feat loads, scalar cls via readfirstlane (row is
// wave-uniform since d4 % 64 == 0); block reduce -> partials; kernel 2 sums.
__global__ __launch_bounds__(256) void fused_kernel(const int* __restrict__ y,
                                                    const vf4* __restrict__ feat4,
                                                    const vf4* __restrict__ cent4,
                                                    float* __restrict__ partials,
                                                    int n4, int d4, float cen_scale,
                                                    int C, int ntile32, int ntri,
                                                    int steps16, float ct, float ang_scale) {
    const int bid = blockIdx.x;
    const int lane = threadIdx.x & 63;
    const int wid = threadIdx.x >> 6;
    __shared__ float sm[4];

    float partial = 0.f;

    // ---------------- angular: one upper-tri 32x32 tile per wave ----------------
    const int t = bid * 4 + wid;            // global wave id == triangular tile id
    if (t < ntri) {
        const int N = ntile32;
        // decode t -> (ti,tj), ti<=tj; base(ti)=ti*N - ti*(ti-1)/2
        const float ff = (float)((2 * N + 1) * (2 * N + 1) - 8 * t);
        int ti = (int)(((float)(2 * N + 1) - sqrtf(ff)) * 0.5f);
        int base = ti * N - (ti * (ti - 1)) / 2;
        if (t < base) {
            --ti; base = ti * N - (ti * (ti - 1)) / 2;
        } else {
            const int nxt = (ti + 1) * N - ((ti + 1) * ti) / 2;
            if (t >= nxt) { ++ti; base = nxt; }
        }
        const int tj = ti + (t - base);

        const int m = lane & 31;            // A/B row within panel
        const int half = lane >> 5;         // k-half selector
        const int ra = ti * 32 + m;
        const int rb = tj * 32 + m;
        const bool va = ra < C;
        const bool vb = rb < C;
        const vf4* aptr = cent4 + (size_t)ra * d4 + half * 2;
        const vf4* bptr = cent4 + (size_t)rb * d4 + half * 2;
        f32x16 acc;
#pragma unroll
        for (int k = 0; k < 16; ++k) acc[k] = 0.f;
        float sa = 0.f, sb = 0.f;
#pragma unroll 4
        for (int st = 0; st < steps16; ++st) {
            vf4 a0 = {0.f, 0.f, 0.f, 0.f}, a1 = a0, b0 = a0, b1 = a0;
            if (va) { a0 = aptr[st * 4]; a1 = aptr[st * 4 + 1]; }
            if (vb) { b0 = bptr[st * 4]; b1 = bptr[st * 4 + 1]; }
            sa += a0.x * a0.x + a0.y * a0.y + a0.z * a0.z + a0.w * a0.w
                + a1.x * a1.x + a1.y * a1.y + a1.z * a1.z + a1.w * a1.w;
            sb += b0.x * b0.x + b0.y * b0.y + b0.z * b0.z + b0.w * b0.w
                + b1.x * b1.x + b1.y * b1.y + b1.z * b1.z + b1.w * b1.w;
            u32x4 ap, bp;
            ap.x = pk_trunc(a0.x, a0.y); ap.y = pk_trunc(a0.z, a0.w);
            ap.z = pk_trunc(a1.x, a1.y); ap.w = pk_trunc(a1.z, a1.w);
            bp.x = pk_trunc(b0.x, b0.y); bp.y = pk_trunc(b0.z, b0.w);
            bp.z = pk_trunc(b1.x, b1.y); bp.w = pk_trunc(b1.z, b1.w);
            bf16x8 af = __builtin_bit_cast(bf16x8, ap);
            bf16x8 bf = __builtin_bit_cast(bf16x8, bp);
            acc = __builtin_amdgcn_mfma_f32_32x32x16_bf16(af, bf, acc, 0, 0, 0);
        }
        // combine the two k-halves of each row norm: lanes l and l^32 share row l&31
        sa += __shfl_xor(sa, 32, 64);
        sb += __shfl_xor(sb, 32, 64);
        // C/D layout (measured m74/m101): col = lane&31, row = (reg&3)+8*(reg>>2)+4*half
        const int gj = tj * 32 + m;
        const float dj = sb;                // norm of B row gj (col of this lane)
        float local = 0.f;
#pragma unroll
        for (int reg = 0; reg < 16; ++reg) {
            const int r = (reg & 3) + 8 * (reg >> 2) + 4 * half;
            const int gi = ti * 32 + r;
            const float di = __shfl(sa, r, 64);   // lane r holds norm of A row r
            if (gi < C && gj < C && gi != gj) {
                float sim = acc[reg] * rsqrtf(di * dj);
                float dlt = sim - ct;
                local += dlt * dlt;
            }
        }
        const float w = (ti == tj) ? 1.f : 2.f;   // off-diag tiles stand in for their mirror
        partial = local * (ang_scale * w);
    }

    // ---------------- center: grid-stride over float4 elements of feat ----------------
    {
        const int stride = gridDim.x * 256;
        float cs = 0.f;
        int i = bid * 256 + threadIdx.x;
        const bool fast = ((stride % d4) == 0) && ((d4 & 63) == 0) && (n4 == 4 * stride);
        if (fast) {
            // exactly 4 iters/thread, all threads in-range, row wave-uniform.
            int row = i / d4;
            const int col = i - row * d4;
            const int rstep = stride / d4;
            // issue all feat streams first (nontemporal: protects the gather's L2)
            const vf4 f0 = __builtin_nontemporal_load(feat4 + i);
            const vf4 f1 = __builtin_nontemporal_load(feat4 + i + stride);
            const vf4 f2 = __builtin_nontemporal_load(feat4 + i + 2 * stride);
            const vf4 f3 = __builtin_nontemporal_load(feat4 + i + 3 * stride);
            // scalar class ids (row is wave-uniform: d4 % 64 == 0)
            const int r0 = __builtin_amdgcn_readfirstlane(row);
            const int cls0 = y[r0];
            const int cls1 = y[r0 + rstep];
            const int cls2 = y[r0 + 2 * rstep];
            const int cls3 = y[r0 + 3 * rstep];
            const vf4 g0 = cent4[(size_t)cls0 * d4 + col];
            const vf4 g1 = cent4[(size_t)cls1 * d4 + col];
            const vf4 g2 = cent4[(size_t)cls2 * d4 + col];
            const vf4 g3 = cent4[(size_t)cls3 * d4 + col];
            float dx, dy, dz, dw;
            dx = f0.x - g0.x; dy = f0.y - g0.y; dz = f0.z - g0.z; dw = f0.w - g0.w;
            cs += dx * dx + dy * dy + dz * dz + dw * dw;
            dx = f1.x - g1.x; dy = f1.y - g1.y; dz = f1.z - g1.z; dw = f1.w - g1.w;
            cs += dx * dx + dy * dy + dz * dz + dw * dw;
            dx = f2.x - g2.x; dy = f2.y - g2.y; dz = f2.z - g2.z; dw = f2.w - g2.w;
            cs += dx * dx + dy * dy + dz * dz + dw * dw;
            dx = f3.x - g3.x; dy = f3.y - g3.y; dz = f3.z - g3.z; dw = f3.w - g3.w;
            cs += dx * dx + dy * dy + dz * dz + dw * dw;
        } else {
            for (; i < n4; i += stride) {
                int row = i / d4;
                int col = i - row * d4;
                const int cls = y[row];
                vf4 f = __builtin_nontemporal_load(feat4 + i);
                vf4 c = cent4[(size_t)cls * d4 + col];
                float dx = f.x - c.x, dy = f.y - c.y, dz = f.z - c.z, dw = f.w - c.w;
                cs += dx * dx + dy * dy + dz * dz + dw * dw;
            }
        }
        partial += cs * cen_scale;
    }

    // block reduce -> plain store to partials[bid] (no atomics anywhere)
    float r = wave_reduce(partial);
    if (lane == 0) sm[wid] = r;
    __syncthreads();
    if (threadIdx.x == 0) {
        partials[bid] = sm[0] + sm[1] + sm[2] + sm[3];
    }
}

// Kernel 2: single block reduces nb partials -> out[0] (plain store).
__global__ __launch_bounds__(256) void reduce_kernel(const float* __restrict__ partials,
                                                     float* __restrict__ out, int nb) {
    __shared__ float sm[4];
    const int lane = threadIdx.x & 63;
    const int wid = threadIdx.x >> 6;
    float s = 0.f;
    for (int i = threadIdx.x; i < nb; i += 256) s += partials[i];
    s = wave_reduce(s);
    if (lane == 0) sm[wid] = s;
    __syncthreads();
    if (threadIdx.x == 0) out[0] = sm[0] + sm[1] + sm[2] + sm[3];
}

extern "C" void kernel_launch(void* const* d_in, const int* in_sizes, int n_in,
                              void* d_out, int out_size, void* d_ws, size_t ws_size,
                              hipStream_t stream) {
    const int* y = (const int*)d_in[0];
    const float* feat = (const float*)d_in[1];
    const float* centers = (const float*)d_in[2];

    const int B = in_sizes[0];
    const int D = in_sizes[1] / B;
    const int C = in_sizes[2] / D;
    const int d4 = D / 4;
    const int ntile32 = (C + 31) / 32;
    const int ntri = ntile32 * (ntile32 + 1) / 2;   // 528 upper-tri tiles for C=1000

    // ct = costheta(C): static recurrence in double, matches Python reference.
    const int nd = C - 1;
    double r = 0.0;
    if (nd >= 2) {
        r = 0.5;
        for (int i = 3; i <= nd; ++i) r = 0.5 / sqrt(1.0 - r * r);
    }
    const float ct = (float)(2.0 * r * r - 1.0);

    const float cen_scale = (float)(0.5 / (double)B);
    const float ang_scale = (float)(1.0 / (0.5 * (double)C * (double)(C - 1)));

    float* partials = (float*)d_ws;
    const int nb = 8192;   // 4 center iters/thread (n4 == 4*stride for B=65536,D=512);
                           // ang on waves 0..527 (blocks 0..131)

    fused_kernel<<<nb, 256, 0, stream>>>(
        y, (const vf4*)feat, (const vf4*)centers, partials,
        B * d4, d4, cen_scale, C, ntile32, ntri, D / 16, ct, ang_scale);

    reduce_kernel<<<1, 256, 0, stream>>>(partials, (float*)d_out, nb);
}